// Round 11
// baseline (108.815 us; speedup 1.0000x reference)
//
#include <hip/hip_runtime.h>

#define N_B    4
#define M_PTS  8192
#define K_PTS  8192
#define CCHUNK 1024               // cols per block
#define NTILE  (CCHUNK / 32)      // 32 col-tiles per wave sweep

// Schraudolph exp2: e = bitcast(int(EXPA - FS*d)), validated R4-R10
#define FS    (7.21347520444481703f * 8388608.0f)
#define EXPA  1064879260.0f       // (127 - 0.0565)*2^23, zero-mean rel err
#define SQB   0x1FBD1DF5u         // bit sqrt: d~ = bitcast((bits(s)>>1)+SQB)
#define LN2   0.69314718055994531f

typedef _Float16 f16x8  __attribute__((ext_vector_type(8)));
typedef float    f32x16 __attribute__((ext_vector_type(16)));
typedef float    v2f    __attribute__((ext_vector_type(2)));

__device__ __forceinline__ f16x8 mk_b(uint2 v) {
    union { uint4 u; f16x8 h; } w;
    w.u = make_uint4(v.x, v.y, 0u, 0u);   // k=0..3 payload; k>=4 don't-care/zero
    return w.h;
}

// post one 32x32 s-tile: e = exp(-ALPHA*sqrt(s)); rs2 packed (pk_add),
// col partial committed with ONE unconditional 64-lane ds_add (half-split).
__device__ __forceinline__ void post_tile(const f32x16& acc, int tp,
                                          v2f* rs2, float* col_half, int l31)
{
    v2f e2[8];
    #pragma unroll
    for (int q = 0; q < 8; ++q) {
        const float s0 = fmaxf(acc[2*q+0], 0.0f);   // f16 cancellation guard
        const float s1 = fmaxf(acc[2*q+1], 0.0f);
        v2f e;
        e.x = __uint_as_float((unsigned)(int)fmaf(
                 __uint_as_float((__float_as_uint(s0) >> 1) + SQB), -FS, EXPA));
        e.y = __uint_as_float((unsigned)(int)fmaf(
                 __uint_as_float((__float_as_uint(s1) >> 1) + SQB), -FS, EXPA));
        e2[q] = e;
        rs2[q] += e;                                 // v_pk_add_f32
    }
    const v2f t = ((e2[0]+e2[1]) + (e2[2]+e2[3]))
                + ((e2[4]+e2[5]) + (e2[6]+e2[7]));   // 7 pk adds
    atomicAdd(&col_half[tp * 32 + l31], t.x + t.y);  // 2-way bank alias: free
}

// R10 post-mortem: algorithm right, execution lost ~200 cyc/tile to serial
// mfma dependency + per-tile shfl/exec-mask + divergent pad reads. R11:
// 2-deep pipelined mfma (named accA/accB), half-split col_acc (no shfl, no
// exec dance), uniform broadcast B-read (lanes>=32 are k=8..15 = don't-care
// since A's k-half is zero there).
__global__ __launch_bounds__(256, 6) void softhaus_pair(
    const float* __restrict__ pred, const float* __restrict__ gt,
    float* __restrict__ row_sum, float* __restrict__ col_sum)
{
    __shared__ uint2 bfr[CCHUNK];
    __shared__ float col_acc[2 * CCHUNK];   // [0]:lanes<32, [CCHUNK]:lanes>=32

    const int n    = blockIdx.z;
    const int rb   = blockIdx.x;          // row-block (128 rows)
    const int cc   = blockIdx.y;          // col-chunk (1024 cols)
    const int tid  = threadIdx.x;
    const int lane = tid & 63;
    const int wv   = tid >> 6;
    const int l31  = lane & 31;

    const float2* P = (const float2*)pred + (size_t)n * M_PTS;
    const float2* G = (const float2*)gt   + (size_t)n * K_PTS;
    const int cbase = cc * CCHUNK;

    // stage B-frags [gx, gy, 1, Ng] (f16x4)
    for (int i = tid; i < CCHUNK; i += 256) {
        const float2 g = G[cbase + i];
        const float ng = fmaf(g.x, g.x, g.y * g.y);
        union { _Float16 h[4]; uint2 u; } w;
        w.h[0] = (_Float16)g.x; w.h[1] = (_Float16)g.y;
        w.h[2] = (_Float16)1.0f; w.h[3] = (_Float16)ng;
        bfr[i] = w.u;
    }
    #pragma unroll
    for (int i = 0; i < 2 * CCHUNK / 256; ++i)
        col_acc[tid + i * 256] = 0.0f;

    // A-frag: wave's 32 rows, [-2px, -2py, Np, 1] in k=0..3 (lanes<32 only;
    // lanes>=32 carry k=8..15 which must be zero)
    const int wrow0 = rb * 128 + wv * 32;
    const float2 p = P[wrow0 + l31];
    f16x8 a = {};
    if (lane < 32) {
        a[0] = (_Float16)(-2.0f * p.x);
        a[1] = (_Float16)(-2.0f * p.y);
        a[2] = (_Float16)fmaf(p.x, p.x, p.y * p.y);
        a[3] = (_Float16)1.0f;
    }

    __syncthreads();

    v2f rs2[8];
    #pragma unroll
    for (int q = 0; q < 8; ++q) { rs2[q].x = 0.0f; rs2[q].y = 0.0f; }

    float* col_half = col_acc + ((lane >= 32) ? CCHUNK : 0);
    const int toff = wv * 8;              // stagger waves (ds_add spread)
    const f32x16 zacc = {};

    // 2-deep software pipeline: issue tile t+1's mfma before post(t)
    int tpA = toff;
    f32x16 accA = __builtin_amdgcn_mfma_f32_32x32x16_f16(
        a, mk_b(bfr[tpA * 32 + l31]), zacc, 0, 0, 0);

    #pragma unroll 2
    for (int t = 0; t < NTILE - 2; t += 2) {
        const int tpB = (t + 1 + toff) & (NTILE - 1);
        f32x16 accB = __builtin_amdgcn_mfma_f32_32x32x16_f16(
            a, mk_b(bfr[tpB * 32 + l31]), zacc, 0, 0, 0);
        post_tile(accA, tpA, rs2, col_half, l31);

        const int tpN = (t + 2 + toff) & (NTILE - 1);
        accA = __builtin_amdgcn_mfma_f32_32x32x16_f16(
            a, mk_b(bfr[tpN * 32 + l31]), zacc, 0, 0, 0);
        post_tile(accB, tpB, rs2, col_half, l31);
        tpA = tpN;
    }
    {   // epilogue: tiles NTILE-2, NTILE-1
        const int tpB = (NTILE - 1 + toff) & (NTILE - 1);
        f32x16 accB = __builtin_amdgcn_mfma_f32_32x32x16_f16(
            a, mk_b(bfr[tpB * 32 + l31]), zacc, 0, 0, 0);
        post_tile(accA, tpA, rs2, col_half, l31);
        post_tile(accB, tpB, rs2, col_half, l31);
    }

    // row sums: reduce each reg over the 32-lane col dimension, commit
    float rs[16];
    #pragma unroll
    for (int q = 0; q < 8; ++q) { rs[2*q] = rs2[q].x; rs[2*q+1] = rs2[q].y; }
    #pragma unroll
    for (int r = 0; r < 16; ++r) {
        #pragma unroll
        for (int m = 1; m <= 16; m <<= 1)
            rs[r] += __shfl_xor(rs[r], m, 32);
    }
    if (l31 == 0) {                       // lanes 0 and 32
        const int half4 = (lane >> 5) << 2;
        float* rsum = row_sum + (size_t)n * M_PTS;
        #pragma unroll
        for (int r = 0; r < 16; ++r) {
            const int row = wrow0 + (r & 3) + ((r >> 2) << 3) + half4;
            atomicAdd(&rsum[row], rs[r]);  // 8 writers/addr (col-chunks)
        }
    }

    __syncthreads();
    for (int i = tid; i < CCHUNK; i += 256)
        atomicAdd(&col_sum[(size_t)n * K_PTS + cbase + i],
                  col_acc[i] + col_acc[CCHUNK + i]);
}

// ws: row_sum (N*M) then col_sum (N*K); equal counts -> single 1/(N*M) scale.
__global__ __launch_bounds__(256) void softhaus_finalize(
    const float* __restrict__ sums, float* __restrict__ out)
{
    const int total  = N_B * M_PTS + N_B * K_PTS;
    const int idx    = blockIdx.x * blockDim.x + threadIdx.x;
    const int stride = gridDim.x * blockDim.x;

    float acc = 0.0f;
    for (int i = idx; i < total; i += stride)
        acc -= __builtin_amdgcn_logf(sums[i]) * LN2;   // -log(v)

    #pragma unroll
    for (int off = 32; off > 0; off >>= 1)
        acc += __shfl_down(acc, off);

    __shared__ float wsum[4];
    const int lane = threadIdx.x & 63;
    const int wv   = threadIdx.x >> 6;
    if (lane == 0) wsum[wv] = acc;
    __syncthreads();
    if (threadIdx.x == 0) {
        float b = wsum[0] + wsum[1] + wsum[2] + wsum[3];
        atomicAdd(out, b * (1.0f / (N_B * M_PTS)));
    }
}

extern "C" void kernel_launch(void* const* d_in, const int* in_sizes, int n_in,
                              void* d_out, int out_size, void* d_ws, size_t ws_size,
                              hipStream_t stream) {
    const float* pred = (const float*)d_in[0];
    const float* gt   = (const float*)d_in[1];
    float* ws = (float*)d_ws;

    const size_t acc_bytes = (size_t)(N_B * M_PTS + N_B * K_PTS) * sizeof(float);
    hipMemsetAsync(d_ws, 0, acc_bytes, stream);
    hipMemsetAsync(d_out, 0, sizeof(float), stream);

    dim3 grid(M_PTS / 128, K_PTS / CCHUNK, N_B);   // 64 x 8 x 4 = 2048 blocks
    softhaus_pair<<<grid, 256, 0, stream>>>(pred, gt, ws, ws + (size_t)N_B * M_PTS);
    softhaus_finalize<<<64, 256, 0, stream>>>(ws, (float*)d_out);
}

// Round 12
// 68.060 us; speedup vs baseline: 1.5988x; 1.5988x over previous
//
#include <hip/hip_runtime.h>

#define N_B    4
#define M_PTS  8192
#define K_PTS  8192
#define RPL    8                  // rows per lane (4 packed row-pairs)
#define BLK_ROWS  (64 * RPL)      // 512 rows per block (shared by 4 waves)
#define BLK_COLS  (4 * 64)        // 256 columns per block (64 per wave)

// exp(-ALPHA*d) via Schraudolph: e = bitcast(int(EXPA - FS*d))  (R4-R11)
#define FS    (7.21347520444481703f * 8388608.0f)
#define EXPA  1064879260.0f       // (127 - 0.0565)*2^23, zero-mean rel err
#define SQB   0x1FBD1DF5u         // bit sqrt: d~ = bitcast((bits(s)>>1)+SQB)
#define LN2   0.69314718055994531f

typedef float v2f __attribute__((ext_vector_type(2)));

// R11 post-mortem: MFMA arc dead (AGPR shuttling). R7 ledger showed 221
// busy-cyc/jj measured vs 124 counted-with-pk ~= 190 counted-scalarized:
// hipcc scalarizes ext_vector f32 math. Force VOP3P packed-f32 via asm.
__device__ __forceinline__ v2f pk_add(v2f a, v2f b) {
    v2f d;
    asm("v_pk_add_f32 %0, %1, %2" : "=v"(d) : "v"(a), "v"(b));
    return d;
}
__device__ __forceinline__ v2f pk_mul(v2f a, v2f b) {
    v2f d;
    asm("v_pk_mul_f32 %0, %1, %2" : "=v"(d) : "v"(a), "v"(b));
    return d;
}
__device__ __forceinline__ v2f pk_fma(v2f a, v2f b, v2f c) {
    v2f d;
    asm("v_pk_fma_f32 %0, %1, %2, %3" : "=v"(d) : "v"(a), "v"(b), "v"(c));
    return d;
}

// one-lane whole-wave rotate (DPP wave_ror:1), proven R3-R11
__device__ __forceinline__ float ror1(float x) {
    int i = __float_as_int(x);
    return __int_as_float(__builtin_amdgcn_update_dpp(i, i, 0x13C, 0xF, 0xF, false));
}

__global__ __launch_bounds__(256) void softhaus_pair(
    const float* __restrict__ pred, const float* __restrict__ gt,
    float* __restrict__ row_sum, float* __restrict__ col_sum)
{
    const int n    = blockIdx.z;
    const int rb   = blockIdx.x * BLK_ROWS;
    const int lane = threadIdx.x & 63;
    const int wv   = threadIdx.x >> 6;

    const float2* P = (const float2*)pred + (size_t)n * M_PTS;
    const float2* G = (const float2*)gt   + (size_t)n * K_PTS;

    v2f px2[RPL / 2], py2[RPL / 2], rs2[RPL / 2];
    #pragma unroll
    for (int i = 0; i < RPL / 2; ++i) {
        float2 a = P[rb + (2 * i    ) * 64 + lane];
        float2 b = P[rb + (2 * i + 1) * 64 + lane];
        px2[i].x = a.x;  px2[i].y = b.x;
        py2[i].x = a.y;  py2[i].y = b.y;
        rs2[i].x = 0.0f; rs2[i].y = 0.0f;
    }

    const int c0 = blockIdx.y * BLK_COLS + wv * 64;
    float2 g0 = G[c0 + lane];
    float gnx = -g0.x;          // negated: dx = px + (-gx) -> plain pk_add
    float gny = -g0.y;          // rotation is linear, so rotating -g is fine
    float cacc = 0.0f;

    #pragma unroll 4
    for (int jj = 0; jj < 64; ++jj) {
        v2f gx2; gx2.x = gnx; gx2.y = gnx;
        v2f gy2; gy2.x = gny; gy2.y = gny;
        v2f e2[RPL / 2];
        #pragma unroll
        for (int i = 0; i < RPL / 2; ++i) {
            const v2f dx = pk_add(px2[i], gx2);           // v_pk_add_f32
            const v2f dy = pk_add(py2[i], gy2);           // v_pk_add_f32
            const v2f s  = pk_fma(dy, dy, pk_mul(dx, dx)); // pk_mul + pk_fma
            // bit sqrt + Schraudolph exp (scalar tail; packing these costs
            // more in pair-assembly movs than it saves)
            const unsigned h0 = (__float_as_uint(s.x) >> 1) + SQB;
            const unsigned h1 = (__float_as_uint(s.y) >> 1) + SQB;
            const float u0 = fmaf(__uint_as_float(h0), -FS, EXPA);
            const float u1 = fmaf(__uint_as_float(h1), -FS, EXPA);
            v2f e;
            e.x = __uint_as_float((unsigned)(int)u0);
            e.y = __uint_as_float((unsigned)(int)u1);
            e2[i] = e;
            rs2[i] = pk_add(rs2[i], e);                   // v_pk_add_f32
        }
        const v2f t = pk_add(pk_add(e2[0], e2[1]), pk_add(e2[2], e2[3]));
        cacc += t.x + t.y;
        // rotate gt point + its accumulator one lane; 64 rotations = identity
        gnx  = ror1(gnx);
        gny  = ror1(gny);
        cacc = ror1(cacc);
    }

    atomicAdd(&col_sum[(size_t)n * K_PTS + c0 + lane], cacc);   // 16 writers
    #pragma unroll
    for (int i = 0; i < RPL / 2; ++i) {                          // 32 writers
        atomicAdd(&row_sum[(size_t)n * M_PTS + rb + (2 * i    ) * 64 + lane], rs2[i].x);
        atomicAdd(&row_sum[(size_t)n * M_PTS + rb + (2 * i + 1) * 64 + lane], rs2[i].y);
    }
}

// ws: row_sum (N*M) then col_sum (N*K); equal counts -> single 1/(N*M) scale.
__global__ __launch_bounds__(256) void softhaus_finalize(
    const float* __restrict__ sums, float* __restrict__ out)
{
    const int total  = N_B * M_PTS + N_B * K_PTS;
    const int idx    = blockIdx.x * blockDim.x + threadIdx.x;
    const int stride = gridDim.x * blockDim.x;

    float acc = 0.0f;
    for (int i = idx; i < total; i += stride)
        acc -= __builtin_amdgcn_logf(sums[i]) * LN2;   // -log(v)

    #pragma unroll
    for (int off = 32; off > 0; off >>= 1)
        acc += __shfl_down(acc, off);

    __shared__ float wsum[4];
    const int lane = threadIdx.x & 63;
    const int wv   = threadIdx.x >> 6;
    if (lane == 0) wsum[wv] = acc;
    __syncthreads();
    if (threadIdx.x == 0) {
        float b = wsum[0] + wsum[1] + wsum[2] + wsum[3];
        atomicAdd(out, b * (1.0f / (N_B * M_PTS)));
    }
}

extern "C" void kernel_launch(void* const* d_in, const int* in_sizes, int n_in,
                              void* d_out, int out_size, void* d_ws, size_t ws_size,
                              hipStream_t stream) {
    const float* pred = (const float*)d_in[0];
    const float* gt   = (const float*)d_in[1];
    float* ws = (float*)d_ws;

    const size_t acc_bytes = (size_t)(N_B * M_PTS + N_B * K_PTS) * sizeof(float);
    hipMemsetAsync(d_ws, 0, acc_bytes, stream);
    hipMemsetAsync(d_out, 0, sizeof(float), stream);

    dim3 grid(M_PTS / BLK_ROWS, K_PTS / BLK_COLS, N_B);  // 16 x 32 x 4 = 2048
    softhaus_pair<<<grid, 256, 0, stream>>>(pred, gt, ws, ws + (size_t)N_B * M_PTS);
    softhaus_finalize<<<64, 256, 0, stream>>>(ws, (float*)d_out);
}